// Round 1
// baseline (328.029 us; speedup 1.0000x reference)
//
#include <hip/hip_runtime.h>
#include <cstdint>
#include <cstddef>

typedef __bf16 bf16;
typedef __bf16 bf16x4 __attribute__((ext_vector_type(4)));
typedef __bf16 bf16x8 __attribute__((ext_vector_type(8)));
typedef float  f32x4  __attribute__((ext_vector_type(4)));

#define B_  2
#define T_  2048
#define D_  1024
#define H_  16
#define HD_ 64
#define M_  (B_ * T_)   // 4096 rows

// ---------------- cast x (fp32 -> bf16) ----------------
__global__ void cast_x_kernel(const float* __restrict__ in, bf16* __restrict__ out) {
    int i = (blockIdx.x * 256 + threadIdx.x) * 4;
    const float4 v = *reinterpret_cast<const float4*>(in + i);
    bf16x4 o = { (bf16)v.x, (bf16)v.y, (bf16)v.z, (bf16)v.w };
    *reinterpret_cast<bf16x4*>(out + i) = o;
}

// ---------------- transpose + cast W: Wt[n][k] = W[k][n] ----------------
__global__ void transpose_cast_kernel(const float* __restrict__ W, bf16* __restrict__ Wt) {
    __shared__ float tile[32][33];
    const int tx = threadIdx.x & 31, ty = threadIdx.x >> 5;  // 32 x 8
    const int bx = blockIdx.x * 32, by = blockIdx.y * 32;
    #pragma unroll
    for (int r = 0; r < 32; r += 8)
        tile[ty + r][tx] = W[(size_t)(by + ty + r) * D_ + bx + tx];
    __syncthreads();
    #pragma unroll
    for (int r = 0; r < 32; r += 8)
        Wt[(size_t)(bx + ty + r) * D_ + by + tx] = (bf16)tile[tx][ty + r];
}

// ---------------- bf16 GEMM, C = A @ Bt^T (+bias)*scale ----------------
// A  [4096][1024] row-major bf16, Bt [1024][1024] row-major bf16 (Bt[n][k] = B[k][n])
// OUT_MODE 0: scatter to QKV ws layout [b][h][t][hd] as bf16
// OUT_MODE 1: fp32 row-major [m][n]
template<int OUT_MODE>
__global__ __launch_bounds__(256) void gemm_bt_kernel(
    const bf16* __restrict__ A, const bf16* __restrict__ Bt,
    const float* __restrict__ bias, void* __restrict__ Cout, float scale)
{
    constexpr int K = D_;
    constexpr int N = D_;
    __shared__ bf16 As[128][64];   // 16 KB
    __shared__ bf16 Bs[128][64];   // 16 KB
    const int tid  = threadIdx.x;
    const int wave = tid >> 6, lane = tid & 63;
    const int lr = lane & 15, lg = lane >> 4;
    const int m0 = blockIdx.x * 128, n0 = blockIdx.y * 128;
    const int wr = wave >> 1, wc = wave & 1;

    f32x4 acc[4][4] = {};

    for (int k0 = 0; k0 < K; k0 += 64) {
        // stage 128x64 A-tile and Bt-tile: 16 chunks of 1KB each, 4 per wave
        #pragma unroll
        for (int cc = 0; cc < 4; ++cc) {
            const int c   = wave * 4 + cc;
            const int row = c * 8 + (lane >> 3);
            const int col = (lane & 7) * 8;
            const bf16* asrc = A  + (size_t)(m0 + row) * K + k0 + col;
            const bf16* bsrc = Bt + (size_t)(n0 + row) * K + k0 + col;
            __builtin_amdgcn_global_load_lds(
                (const __attribute__((address_space(1))) void*)asrc,
                (__attribute__((address_space(3))) void*)(&As[c * 8][0]), 16, 0, 0);
            __builtin_amdgcn_global_load_lds(
                (const __attribute__((address_space(1))) void*)bsrc,
                (__attribute__((address_space(3))) void*)(&Bs[c * 8][0]), 16, 0, 0);
        }
        __syncthreads();
        #pragma unroll
        for (int kk = 0; kk < 64; kk += 32) {
            bf16x8 af[4], bfr[4];
            #pragma unroll
            for (int i = 0; i < 4; ++i)
                af[i] = *reinterpret_cast<const bf16x8*>(&As[wr * 64 + i * 16 + lr][kk + lg * 8]);
            #pragma unroll
            for (int j = 0; j < 4; ++j)
                bfr[j] = *reinterpret_cast<const bf16x8*>(&Bs[wc * 64 + j * 16 + lr][kk + lg * 8]);
            #pragma unroll
            for (int i = 0; i < 4; ++i)
                #pragma unroll
                for (int j = 0; j < 4; ++j)
                    acc[i][j] = __builtin_amdgcn_mfma_f32_16x16x32_bf16(af[i], bfr[j], acc[i][j], 0, 0, 0);
        }
        __syncthreads();
    }

    // epilogue: C/D layout col=lane&15, row=(lane>>4)*4+reg
    #pragma unroll
    for (int i = 0; i < 4; ++i) {
        #pragma unroll
        for (int j = 0; j < 4; ++j) {
            #pragma unroll
            for (int r = 0; r < 4; ++r) {
                const int m = m0 + wr * 64 + i * 16 + lg * 4 + r;
                const int n = n0 + wc * 64 + j * 16 + lr;
                const float val = (acc[i][j][r] + bias[n]) * scale;
                if (OUT_MODE == 0) {
                    const int b = m >> 11, t = m & (T_ - 1);
                    const int h = n >> 6, hd = n & 63;
                    ((bf16*)Cout)[((size_t)((b * H_ + h) * T_ + t)) * HD_ + hd] = (bf16)val;
                } else {
                    ((float*)Cout)[(size_t)m * N + n] = val;
                }
            }
        }
    }
}

// ---------------- flash attention: per (bh, qblock of 64) ----------------
// Q pre-scaled by 1/8. Layouts: Q/K/V [bh][T][64] bf16. Out [b*T+t][h*64+d] bf16.
__global__ __launch_bounds__(256) void attn_kernel(
    const bf16* __restrict__ Q, const bf16* __restrict__ K,
    const bf16* __restrict__ V, bf16* __restrict__ Out)
{
    const int qb = blockIdx.x, bh = blockIdx.y;
    const int tid = threadIdx.x, wave = tid >> 6, lane = tid & 63;
    const int lr = lane & 15, lg = lane >> 4;
    const int q0 = qb * 64;
    const size_t base = (size_t)bh * T_ * HD_;

    __shared__ bf16 Ks[64][64];      // 8 KB (linear: global_load_lds target)
    __shared__ bf16 Vt[64][72];      // 9 KB transposed V (padded)
    __shared__ bf16 Ps[4][16][64];   // 8 KB per-wave P

    // Q fragments for this wave's 16 rows (A-layout: row=lane&15, k=(lane>>4)*8+i)
    bf16x8 qf[2];
    {
        const bf16* qrow = Q + base + (size_t)(q0 + wave * 16 + lr) * HD_;
        qf[0] = *reinterpret_cast<const bf16x8*>(qrow + lg * 8);
        qf[1] = *reinterpret_cast<const bf16x8*>(qrow + 32 + lg * 8);
    }

    float m_r[4] = {-1e30f, -1e30f, -1e30f, -1e30f};
    float l_r[4] = {0.f, 0.f, 0.f, 0.f};
    f32x4 o_acc[4] = {};

    for (int kt = 0; kt <= qb; ++kt) {
        const int kv0 = kt * 64;
        // stage K tile (linear, 8 chunks of 1KB; 2 per wave)
        #pragma unroll
        for (int cc = 0; cc < 2; ++cc) {
            const int c   = wave * 2 + cc;
            const int row = c * 8 + (lane >> 3);
            const int col = (lane & 7) * 8;
            const bf16* src = K + base + (size_t)(kv0 + row) * HD_ + col;
            __builtin_amdgcn_global_load_lds(
                (const __attribute__((address_space(1))) void*)src,
                (__attribute__((address_space(3))) void*)(&Ks[c * 8][0]), 16, 0, 0);
        }
        // stage V transposed: Vt[d][key]
        for (int i = tid; i < 64 * 64; i += 256) {
            const int key = i >> 6, d = i & 63;
            Vt[d][key] = V[base + (size_t)(kv0 + key) * HD_ + d];
        }
        __syncthreads();

        // S = Q K^T  (16 q-rows x 64 keys per wave)
        f32x4 s[4] = {};
        #pragma unroll
        for (int n16 = 0; n16 < 4; ++n16) {
            #pragma unroll
            for (int kk = 0; kk < 2; ++kk) {
                bf16x8 bfr = *reinterpret_cast<const bf16x8*>(&Ks[n16 * 16 + lr][kk * 32 + lg * 8]);
                s[n16] = __builtin_amdgcn_mfma_f32_16x16x32_bf16(qf[kk], bfr, s[n16], 0, 0, 0);
            }
        }
        // causal mask on diagonal tile
        if (kt == qb) {
            #pragma unroll
            for (int n16 = 0; n16 < 4; ++n16)
                #pragma unroll
                for (int r = 0; r < 4; ++r)
                    if (kv0 + n16 * 16 + lr > q0 + wave * 16 + lg * 4 + r)
                        s[n16][r] = -1e30f;
        }
        // online softmax (rows live across the 16 lanes lane&15; per-reg row)
        #pragma unroll
        for (int r = 0; r < 4; ++r) {
            float mx = fmaxf(fmaxf(s[0][r], s[1][r]), fmaxf(s[2][r], s[3][r]));
            mx = fmaxf(mx, __shfl_xor(mx, 1));
            mx = fmaxf(mx, __shfl_xor(mx, 2));
            mx = fmaxf(mx, __shfl_xor(mx, 4));
            mx = fmaxf(mx, __shfl_xor(mx, 8));
            const float mnew  = fmaxf(m_r[r], mx);
            const float alpha = __expf(m_r[r] - mnew);
            float rs = 0.f;
            #pragma unroll
            for (int n16 = 0; n16 < 4; ++n16) {
                const float p = __expf(s[n16][r] - mnew);
                s[n16][r] = p;
                rs += p;
            }
            rs += __shfl_xor(rs, 1);
            rs += __shfl_xor(rs, 2);
            rs += __shfl_xor(rs, 4);
            rs += __shfl_xor(rs, 8);
            l_r[r] = l_r[r] * alpha + rs;
            m_r[r] = mnew;
            #pragma unroll
            for (int nd = 0; nd < 4; ++nd) o_acc[nd][r] *= alpha;
        }
        // P -> LDS (A-fragment staging)
        #pragma unroll
        for (int n16 = 0; n16 < 4; ++n16)
            #pragma unroll
            for (int r = 0; r < 4; ++r)
                Ps[wave][lg * 4 + r][n16 * 16 + lr] = (bf16)s[n16][r];
        __syncthreads();
        // O += P @ V
        #pragma unroll
        for (int ks = 0; ks < 2; ++ks) {
            bf16x8 pa = *reinterpret_cast<const bf16x8*>(&Ps[wave][lr][ks * 32 + lg * 8]);
            #pragma unroll
            for (int nd = 0; nd < 4; ++nd) {
                bf16x8 vb = *reinterpret_cast<const bf16x8*>(&Vt[nd * 16 + lr][ks * 32 + lg * 8]);
                o_acc[nd] = __builtin_amdgcn_mfma_f32_16x16x32_bf16(pa, vb, o_acc[nd], 0, 0, 0);
            }
        }
        __syncthreads();
    }

    // normalize + store to [b*T+t][h*64+d]
    const int b = bh >> 4, h = bh & 15;
    #pragma unroll
    for (int nd = 0; nd < 4; ++nd)
        #pragma unroll
        for (int r = 0; r < 4; ++r) {
            const int q = q0 + wave * 16 + lg * 4 + r;
            const int d = nd * 16 + lr;
            const float val = o_acc[nd][r] / l_r[r];
            Out[((size_t)(b * T_ + q)) * D_ + h * HD_ + d] = (bf16)val;
        }
}

// ---------------- launch ----------------
extern "C" void kernel_launch(void* const* d_in, const int* in_sizes, int n_in,
                              void* d_out, int out_size, void* d_ws, size_t ws_size,
                              hipStream_t stream) {
    const float* x  = (const float*)d_in[0];
    const float* Wq = (const float*)d_in[1];
    const float* bq = (const float*)d_in[2];
    const float* Wk = (const float*)d_in[3];
    const float* bk = (const float*)d_in[4];
    const float* Wv = (const float*)d_in[5];
    const float* bv = (const float*)d_in[6];
    const float* Wo = (const float*)d_in[7];
    const float* bo = (const float*)d_in[8];
    float* out = (float*)d_out;

    char* ws = (char*)d_ws;
    bf16* xb   = (bf16*)(ws);                         // 8 MB  [4096][1024]
    bf16* WqT  = (bf16*)(ws + ( 8u << 20));           // 2 MB  [1024][1024]
    bf16* WkT  = (bf16*)(ws + (10u << 20));
    bf16* WvT  = (bf16*)(ws + (12u << 20));
    bf16* WoT  = (bf16*)(ws + (14u << 20));
    bf16* Qb   = (bf16*)(ws + (16u << 20));           // 8 MB  [32][2048][64]
    bf16* Kb   = (bf16*)(ws + (24u << 20));
    bf16* Vb   = (bf16*)(ws + (32u << 20));
    bf16* attn = (bf16*)(ws + (40u << 20));           // 8 MB  [4096][1024]

    cast_x_kernel<<<4096, 256, 0, stream>>>(x, xb);
    transpose_cast_kernel<<<dim3(32, 32), 256, 0, stream>>>(Wq, WqT);
    transpose_cast_kernel<<<dim3(32, 32), 256, 0, stream>>>(Wk, WkT);
    transpose_cast_kernel<<<dim3(32, 32), 256, 0, stream>>>(Wv, WvT);
    transpose_cast_kernel<<<dim3(32, 32), 256, 0, stream>>>(Wo, WoT);

    const float qscale = 0.125f;  // Hd^-0.5, folded into Q
    gemm_bt_kernel<0><<<dim3(32, 8), 256, 0, stream>>>(xb, WqT, bq, Qb, qscale);
    gemm_bt_kernel<0><<<dim3(32, 8), 256, 0, stream>>>(xb, WkT, bk, Kb, 1.0f);
    gemm_bt_kernel<0><<<dim3(32, 8), 256, 0, stream>>>(xb, WvT, bv, Vb, 1.0f);

    attn_kernel<<<dim3(32, 32), 256, 0, stream>>>(Qb, Kb, Vb, attn);

    gemm_bt_kernel<1><<<dim3(32, 8), 256, 0, stream>>>(attn, WoT, bo, out, 1.0f);
}

// Round 2
// 166.139 us; speedup vs baseline: 1.9744x; 1.9744x over previous
//
#include <hip/hip_runtime.h>
#include <cstdint>
#include <cstddef>

typedef __bf16 bf16;
typedef __bf16 bf16x4 __attribute__((ext_vector_type(4)));
typedef __bf16 bf16x8 __attribute__((ext_vector_type(8)));
typedef float  f32x4  __attribute__((ext_vector_type(4)));

#define B_  2
#define T_  2048
#define D_  1024
#define H_  16
#define HD_ 64
#define M_  (B_ * T_)   // 4096 rows
#define NQB 32          // T_/64 q-blocks

#define GLOAD_LDS(gsrc, ldst) \
    __builtin_amdgcn_global_load_lds( \
        (const __attribute__((address_space(1))) void*)(gsrc), \
        (__attribute__((address_space(3))) void*)(ldst), 16, 0, 0)

// ---------------- cast x (fp32 -> bf16) ----------------
__global__ void cast_x_kernel(const float* __restrict__ in, bf16* __restrict__ out) {
    int i = (blockIdx.x * 256 + threadIdx.x) * 4;
    const float4 v = *reinterpret_cast<const float4*>(in + i);
    bf16x4 o = { (bf16)v.x, (bf16)v.y, (bf16)v.z, (bf16)v.w };
    *reinterpret_cast<bf16x4*>(out + i) = o;
}

// ---------------- transpose + cast W: Wt[n][k] = W[k][n] ----------------
__global__ void transpose_cast_kernel(const float* __restrict__ W, bf16* __restrict__ Wt) {
    __shared__ float tile[32][33];
    const int tx = threadIdx.x & 31, ty = threadIdx.x >> 5;  // 32 x 8
    const int bx = blockIdx.x * 32, by = blockIdx.y * 32;
    #pragma unroll
    for (int r = 0; r < 32; r += 8)
        tile[ty + r][tx] = W[(size_t)(by + ty + r) * D_ + bx + tx];
    __syncthreads();
    #pragma unroll
    for (int r = 0; r < 32; r += 8)
        Wt[(size_t)(bx + ty + r) * D_ + by + tx] = (bf16)tile[tx][ty + r];
}

// ---------------- shared 128x128 bf16 GEMM core (K=1024) ----------------
// acc[i][j] = sum_k A[m0+..][k] * Bt[n0+..][k]
__device__ __forceinline__ void gemm_core_128(
    const bf16* __restrict__ A, const bf16* __restrict__ Bt,
    int m0, int n0, bf16 (*As)[64], bf16 (*Bs)[64], f32x4 acc[4][4])
{
    constexpr int K = D_;
    const int tid  = threadIdx.x;
    const int wave = tid >> 6, lane = tid & 63;
    const int lr = lane & 15, lg = lane >> 4;
    const int wr = wave >> 1, wc = wave & 1;

    for (int k0 = 0; k0 < K; k0 += 64) {
        #pragma unroll
        for (int cc = 0; cc < 4; ++cc) {
            const int c   = wave * 4 + cc;
            const int row = c * 8 + (lane >> 3);
            const int col = (lane & 7) * 8;
            GLOAD_LDS(A  + (size_t)(m0 + row) * K + k0 + col, &As[c * 8][0]);
            GLOAD_LDS(Bt + (size_t)(n0 + row) * K + k0 + col, &Bs[c * 8][0]);
        }
        __syncthreads();
        #pragma unroll
        for (int kk = 0; kk < 64; kk += 32) {
            bf16x8 af[4], bfr[4];
            #pragma unroll
            for (int i = 0; i < 4; ++i)
                af[i] = *reinterpret_cast<const bf16x8*>(&As[wr * 64 + i * 16 + lr][kk + lg * 8]);
            #pragma unroll
            for (int j = 0; j < 4; ++j)
                bfr[j] = *reinterpret_cast<const bf16x8*>(&Bs[wc * 64 + j * 16 + lr][kk + lg * 8]);
            #pragma unroll
            for (int i = 0; i < 4; ++i)
                #pragma unroll
                for (int j = 0; j < 4; ++j)
                    acc[i][j] = __builtin_amdgcn_mfma_f32_16x16x32_bf16(af[i], bfr[j], acc[i][j], 0, 0, 0);
        }
        __syncthreads();
    }
}

// ---------------- fused Q+K projection: scatter to [b][h][t][hd] bf16 ----------------
__global__ __launch_bounds__(256) void gemm_qk_kernel(
    const bf16* __restrict__ A,
    const bf16* __restrict__ WqT, const float* __restrict__ bq, bf16* __restrict__ Qo,
    const bf16* __restrict__ WkT, const float* __restrict__ bk, bf16* __restrict__ Ko)
{
    __shared__ bf16 As[128][64];
    __shared__ bf16 Bs[128][64];
    const bool isK = blockIdx.y >= 8;
    const bf16*  Bt   = isK ? WkT : WqT;
    const float* bias = isK ? bk  : bq;
    bf16*        Out  = isK ? Ko  : Qo;
    const float  scale = isK ? 1.0f : 0.125f;
    const int m0 = blockIdx.x * 128, n0 = (blockIdx.y & 7) * 128;

    f32x4 acc[4][4] = {};
    gemm_core_128(A, Bt, m0, n0, As, Bs, acc);

    const int lane = threadIdx.x & 63, wave = threadIdx.x >> 6;
    const int lr = lane & 15, lg = lane >> 4;
    const int wr = wave >> 1, wc = wave & 1;
    #pragma unroll
    for (int i = 0; i < 4; ++i)
        #pragma unroll
        for (int j = 0; j < 4; ++j)
            #pragma unroll
            for (int r = 0; r < 4; ++r) {
                const int m = m0 + wr * 64 + i * 16 + lg * 4 + r;
                const int n = n0 + wc * 64 + j * 16 + lr;
                const float val = (acc[i][j][r] + bias[n]) * scale;
                const int b = m >> 11, t = m & (T_ - 1);
                const int h = n >> 6, hd = n & 63;
                Out[((size_t)((b * H_ + h) * T_ + t)) * HD_ + hd] = (bf16)val;
            }
}

// ---------------- V^T projection: C[d_glob][t] = sum_k WvT[d][k] x[t][k] ----------------
// Out layout: [(b*16+h)*64+hd][T_] = [b*1024+m][2048]
__global__ __launch_bounds__(256) void gemm_vt_kernel(
    const bf16* __restrict__ WvT, const bf16* __restrict__ Xb,
    const float* __restrict__ bv, bf16* __restrict__ Vt)
{
    __shared__ bf16 As[128][64];
    __shared__ bf16 Bs[128][64];
    const int m0 = blockIdx.x * 128, n0 = blockIdx.y * 128;  // m over 1024 (d), n over 4096 (b*t)

    f32x4 acc[4][4] = {};
    gemm_core_128(WvT, Xb, m0, n0, As, Bs, acc);

    const int lane = threadIdx.x & 63, wave = threadIdx.x >> 6;
    const int lr = lane & 15, lg = lane >> 4;
    const int wr = wave >> 1, wc = wave & 1;
    #pragma unroll
    for (int i = 0; i < 4; ++i)
        #pragma unroll
        for (int j = 0; j < 4; ++j)
            #pragma unroll
            for (int r = 0; r < 4; ++r) {
                const int m = m0 + wr * 64 + i * 16 + lg * 4 + r;   // d_glob
                const int n = n0 + wc * 64 + j * 16 + lr;            // b*2048 + t
                const float val = acc[i][j][r] + bv[m];
                const int b = n >> 11, t = n & (T_ - 1);
                Vt[((size_t)(b * D_ + m)) * T_ + t] = (bf16)val;
            }
}

// ---------------- out projection: fp32 [m][n] ----------------
__global__ __launch_bounds__(256) void gemm_out_kernel(
    const bf16* __restrict__ A, const bf16* __restrict__ WoT,
    const float* __restrict__ bo, float* __restrict__ Out)
{
    __shared__ bf16 As[128][64];
    __shared__ bf16 Bs[128][64];
    const int m0 = blockIdx.x * 128, n0 = blockIdx.y * 128;

    f32x4 acc[4][4] = {};
    gemm_core_128(A, WoT, m0, n0, As, Bs, acc);

    const int lane = threadIdx.x & 63, wave = threadIdx.x >> 6;
    const int lr = lane & 15, lg = lane >> 4;
    const int wr = wave >> 1, wc = wave & 1;
    #pragma unroll
    for (int i = 0; i < 4; ++i)
        #pragma unroll
        for (int j = 0; j < 4; ++j)
            #pragma unroll
            for (int r = 0; r < 4; ++r) {
                const int m = m0 + wr * 64 + i * 16 + lg * 4 + r;
                const int n = n0 + wc * 64 + j * 16 + lr;
                Out[(size_t)m * D_ + n] = acc[i][j][r] + bo[n];
            }
}

// ---------------- flash attention ----------------
// Q,K: [bh][t][64] bf16 (Q pre-scaled 1/8). Vt: [bh][64][T] bf16.
// Block x handles q-blocks x and 31-x (33 KV tiles total -> balanced).
// Double-buffered K/V staging via global_load_lds w/ XOR source-chunk swizzle.
__global__ __launch_bounds__(256) void attn_kernel(
    const bf16* __restrict__ Q, const bf16* __restrict__ K,
    const bf16* __restrict__ Vt, bf16* __restrict__ Out)
{
    const int bh = blockIdx.y;
    const int tid = threadIdx.x, wave = tid >> 6, lane = tid & 63;
    const int lr = lane & 15, lg = lane >> 4;
    const size_t kbase = (size_t)bh * T_ * HD_;   // Q,K
    const size_t vbase = (size_t)bh * HD_ * T_;   // Vt

    __shared__ bf16 Ks[2][64][64];   // 16 KB
    __shared__ bf16 Vs[2][64][64];   // 16 KB  (Vs[buf][d][key])
    __shared__ bf16 Ps[4][16][72];   // 9 KB   per-wave P, padded

    // stage one 64-key tile into buffer sb (K rows=keys, V rows=d), swizzled source
    auto stage = [&](int sb, int kt) {
        const int kv0 = kt * 64;
        const int rseg = lane >> 3;              // 0..7 (row within 8-row segment)
        const int srcw = (lane & 7) ^ rseg;      // source 16B-chunk (involution)
        #pragma unroll
        for (int cc = 0; cc < 2; ++cc) {
            const int seg = wave * 2 + cc;       // 0..7
            const int row = seg * 8 + rseg;      // 0..63
            GLOAD_LDS(K  + kbase + (size_t)(kv0 + row) * HD_ + srcw * 8, &Ks[sb][seg * 8][0]);
            GLOAD_LDS(Vt + vbase + (size_t)row * T_ + kv0 + srcw * 8,    &Vs[sb][seg * 8][0]);
        }
    };
    // swizzled 16B fragment reads (chunk = col/8)
    auto kfrag = [&](int sb, int row, int chunk) {
        return *reinterpret_cast<const bf16x8*>(&Ks[sb][row][(chunk ^ (row & 7)) * 8]);
    };
    auto vfrag = [&](int sb, int row, int chunk) {
        return *reinterpret_cast<const bf16x8*>(&Vs[sb][row][(chunk ^ (row & 7)) * 8]);
    };

    #pragma unroll 1
    for (int half = 0; half < 2; ++half) {
        const int qb = half == 0 ? blockIdx.x : (NQB - 1 - blockIdx.x);
        const int q0 = qb * 64;
        const int nt = qb + 1;

        // Q fragments for this wave's 16 rows
        bf16x8 qf[2];
        {
            const bf16* qrow = Q + kbase + (size_t)(q0 + wave * 16 + lr) * HD_;
            qf[0] = *reinterpret_cast<const bf16x8*>(qrow + lg * 8);
            qf[1] = *reinterpret_cast<const bf16x8*>(qrow + 32 + lg * 8);
        }

        float m_r[4] = {-1e30f, -1e30f, -1e30f, -1e30f};
        float l_r[4] = {0.f, 0.f, 0.f, 0.f};
        f32x4 o_acc[4] = {};

        stage(0, 0);
        __syncthreads();

        #pragma unroll 1
        for (int t = 0; t < nt; ++t) {
            const int cur = t & 1;
            if (t + 1 < nt) stage(cur ^ 1, t + 1);  // prefetch next tile

            const int kv0 = t * 64;
            // S = Q K^T
            f32x4 s[4] = {};
            #pragma unroll
            for (int n16 = 0; n16 < 4; ++n16)
                #pragma unroll
                for (int kk = 0; kk < 2; ++kk)
                    s[n16] = __builtin_amdgcn_mfma_f32_16x16x32_bf16(
                        qf[kk], kfrag(cur, n16 * 16 + lr, kk * 4 + lg), s[n16], 0, 0, 0);
            // causal mask on diagonal tile
            if (t == qb) {
                #pragma unroll
                for (int n16 = 0; n16 < 4; ++n16)
                    #pragma unroll
                    for (int r = 0; r < 4; ++r)
                        if (kv0 + n16 * 16 + lr > q0 + wave * 16 + lg * 4 + r)
                            s[n16][r] = -1e30f;
            }
            // online softmax
            #pragma unroll
            for (int r = 0; r < 4; ++r) {
                float mx = fmaxf(fmaxf(s[0][r], s[1][r]), fmaxf(s[2][r], s[3][r]));
                mx = fmaxf(mx, __shfl_xor(mx, 1));
                mx = fmaxf(mx, __shfl_xor(mx, 2));
                mx = fmaxf(mx, __shfl_xor(mx, 4));
                mx = fmaxf(mx, __shfl_xor(mx, 8));
                const float mnew  = fmaxf(m_r[r], mx);
                const float alpha = __expf(m_r[r] - mnew);
                float rs = 0.f;
                #pragma unroll
                for (int n16 = 0; n16 < 4; ++n16) {
                    const float p = __expf(s[n16][r] - mnew);
                    s[n16][r] = p;
                    rs += p;
                }
                rs += __shfl_xor(rs, 1);
                rs += __shfl_xor(rs, 2);
                rs += __shfl_xor(rs, 4);
                rs += __shfl_xor(rs, 8);
                l_r[r] = l_r[r] * alpha + rs;
                m_r[r] = mnew;
                #pragma unroll
                for (int nd = 0; nd < 4; ++nd) o_acc[nd][r] *= alpha;
            }
            // P -> LDS (wave-private)
            #pragma unroll
            for (int n16 = 0; n16 < 4; ++n16)
                #pragma unroll
                for (int r = 0; r < 4; ++r)
                    Ps[wave][lg * 4 + r][n16 * 16 + lr] = (bf16)s[n16][r];
            // O += P @ V
            #pragma unroll
            for (int ks = 0; ks < 2; ++ks) {
                const bf16x8 pa = *reinterpret_cast<const bf16x8*>(&Ps[wave][lr][ks * 32 + lg * 8]);
                #pragma unroll
                for (int nd = 0; nd < 4; ++nd)
                    o_acc[nd] = __builtin_amdgcn_mfma_f32_16x16x32_bf16(
                        pa, vfrag(cur, nd * 16 + lr, ks * 4 + lg), o_acc[nd], 0, 0, 0);
            }
            __syncthreads();  // next tile staged (vmcnt drained), buffers safe to swap
        }

        // normalize + store to [b*T+t][h*64+d]
        const int b = bh >> 4, h = bh & 15;
        #pragma unroll
        for (int nd = 0; nd < 4; ++nd)
            #pragma unroll
            for (int r = 0; r < 4; ++r) {
                const int q = q0 + wave * 16 + lg * 4 + r;
                const int d = nd * 16 + lr;
                Out[((size_t)(b * T_ + q)) * D_ + h * HD_ + d] = (bf16)(o_acc[nd][r] / l_r[r]);
            }
    }
}

// ---------------- launch ----------------
extern "C" void kernel_launch(void* const* d_in, const int* in_sizes, int n_in,
                              void* d_out, int out_size, void* d_ws, size_t ws_size,
                              hipStream_t stream) {
    const float* x  = (const float*)d_in[0];
    const float* Wq = (const float*)d_in[1];
    const float* bq = (const float*)d_in[2];
    const float* Wk = (const float*)d_in[3];
    const float* bk = (const float*)d_in[4];
    const float* Wv = (const float*)d_in[5];
    const float* bv = (const float*)d_in[6];
    const float* Wo = (const float*)d_in[7];
    const float* bo = (const float*)d_in[8];
    float* out = (float*)d_out;

    char* ws = (char*)d_ws;
    bf16* xb   = (bf16*)(ws);                         // 8 MB  [4096][1024]
    bf16* WqT  = (bf16*)(ws + ( 8u << 20));           // 2 MB  [1024][1024]
    bf16* WkT  = (bf16*)(ws + (10u << 20));
    bf16* WvT  = (bf16*)(ws + (12u << 20));
    bf16* WoT  = (bf16*)(ws + (14u << 20));
    bf16* Qb   = (bf16*)(ws + (16u << 20));           // 8 MB  [32][2048][64]
    bf16* Kb   = (bf16*)(ws + (24u << 20));
    bf16* Vtb  = (bf16*)(ws + (32u << 20));           // 8 MB  [32][64][2048]
    bf16* attn = (bf16*)(ws + (40u << 20));           // 8 MB  [4096][1024]

    cast_x_kernel<<<4096, 256, 0, stream>>>(x, xb);
    transpose_cast_kernel<<<dim3(32, 32), 256, 0, stream>>>(Wq, WqT);
    transpose_cast_kernel<<<dim3(32, 32), 256, 0, stream>>>(Wk, WkT);
    transpose_cast_kernel<<<dim3(32, 32), 256, 0, stream>>>(Wv, WvT);
    transpose_cast_kernel<<<dim3(32, 32), 256, 0, stream>>>(Wo, WoT);

    gemm_qk_kernel<<<dim3(32, 16), 256, 0, stream>>>(xb, WqT, bq, Qb, WkT, bk, Kb);
    gemm_vt_kernel<<<dim3(8, 32), 256, 0, stream>>>(WvT, xb, bv, Vtb);

    attn_kernel<<<dim3(NQB / 2, 32), 256, 0, stream>>>(Qb, Kb, Vtb, attn);

    gemm_out_kernel<<<dim3(32, 8), 256, 0, stream>>>(attn, WoT, bo, out);
}

// Round 3
// 140.355 us; speedup vs baseline: 2.3371x; 1.1837x over previous
//
#include <hip/hip_runtime.h>
#include <cstdint>
#include <cstddef>

typedef __bf16 bf16;
typedef __bf16 bf16x4 __attribute__((ext_vector_type(4)));
typedef __bf16 bf16x8 __attribute__((ext_vector_type(8)));
typedef float  f32x4  __attribute__((ext_vector_type(4)));

#define B_  2
#define T_  2048
#define D_  1024
#define H_  16
#define HD_ 64
#define M_  (B_ * T_)   // 4096 rows
#define NQB 16          // T_/128 q-super-blocks

#define GLOAD_LDS(gsrc, ldst) \
    __builtin_amdgcn_global_load_lds( \
        (const __attribute__((address_space(1))) void*)(gsrc), \
        (__attribute__((address_space(3))) void*)(ldst), 16, 0, 0)

// ---------------- cast x (fp32 -> bf16) ----------------
__global__ void cast_x_kernel(const float* __restrict__ in, bf16* __restrict__ out) {
    int i = (blockIdx.x * 256 + threadIdx.x) * 4;
    const float4 v = *reinterpret_cast<const float4*>(in + i);
    bf16x4 o = { (bf16)v.x, (bf16)v.y, (bf16)v.z, (bf16)v.w };
    *reinterpret_cast<bf16x4*>(out + i) = o;
}

// ---------------- transpose + cast 4 weights: Wt[n][k] = W[k][n] ----------------
__global__ void transpose_cast_kernel(
    const float* __restrict__ W0, bf16* __restrict__ T0,
    const float* __restrict__ W1, bf16* __restrict__ T1,
    const float* __restrict__ W2, bf16* __restrict__ T2,
    const float* __restrict__ W3, bf16* __restrict__ T3)
{
    __shared__ float tile[32][33];
    const float* W = blockIdx.z == 0 ? W0 : blockIdx.z == 1 ? W1 : blockIdx.z == 2 ? W2 : W3;
    bf16*       Wt = blockIdx.z == 0 ? T0 : blockIdx.z == 1 ? T1 : blockIdx.z == 2 ? T2 : T3;
    const int tx = threadIdx.x & 31, ty = threadIdx.x >> 5;  // 32 x 8
    const int bx = blockIdx.x * 32, by = blockIdx.y * 32;
    #pragma unroll
    for (int r = 0; r < 32; r += 8)
        tile[ty + r][tx] = W[(size_t)(by + ty + r) * D_ + bx + tx];
    __syncthreads();
    #pragma unroll
    for (int r = 0; r < 32; r += 8)
        Wt[(size_t)(bx + ty + r) * D_ + by + tx] = (bf16)tile[tx][ty + r];
}

// ---------------- shared 128x128 bf16 GEMM core (K=1024) ----------------
__device__ __forceinline__ void gemm_core_128(
    const bf16* __restrict__ A, const bf16* __restrict__ Bt,
    int m0, int n0, bf16 (*As)[64], bf16 (*Bs)[64], f32x4 acc[4][4])
{
    constexpr int K = D_;
    const int tid  = threadIdx.x;
    const int wave = tid >> 6, lane = tid & 63;
    const int lr = lane & 15, lg = lane >> 4;
    const int wr = wave >> 1, wc = wave & 1;

    for (int k0 = 0; k0 < K; k0 += 64) {
        #pragma unroll
        for (int cc = 0; cc < 4; ++cc) {
            const int c   = wave * 4 + cc;
            const int row = c * 8 + (lane >> 3);
            const int col = (lane & 7) * 8;
            GLOAD_LDS(A  + (size_t)(m0 + row) * K + k0 + col, &As[c * 8][0]);
            GLOAD_LDS(Bt + (size_t)(n0 + row) * K + k0 + col, &Bs[c * 8][0]);
        }
        __syncthreads();
        #pragma unroll
        for (int kk = 0; kk < 64; kk += 32) {
            bf16x8 af[4], bfr[4];
            #pragma unroll
            for (int i = 0; i < 4; ++i)
                af[i] = *reinterpret_cast<const bf16x8*>(&As[wr * 64 + i * 16 + lr][kk + lg * 8]);
            #pragma unroll
            for (int j = 0; j < 4; ++j)
                bfr[j] = *reinterpret_cast<const bf16x8*>(&Bs[wc * 64 + j * 16 + lr][kk + lg * 8]);
            #pragma unroll
            for (int i = 0; i < 4; ++i)
                #pragma unroll
                for (int j = 0; j < 4; ++j)
                    acc[i][j] = __builtin_amdgcn_mfma_f32_16x16x32_bf16(af[i], bfr[j], acc[i][j], 0, 0, 0);
        }
        __syncthreads();
    }
}

// ---------------- fused Q+K projection: scatter to [b][h][t][hd] bf16 ----------------
__global__ __launch_bounds__(256) void gemm_qk_kernel(
    const bf16* __restrict__ A,
    const bf16* __restrict__ WqT, const float* __restrict__ bq, bf16* __restrict__ Qo,
    const bf16* __restrict__ WkT, const float* __restrict__ bk, bf16* __restrict__ Ko)
{
    __shared__ bf16 As[128][64];
    __shared__ bf16 Bs[128][64];
    const bool isK = blockIdx.y >= 8;
    const bf16*  Bt   = isK ? WkT : WqT;
    const float* bias = isK ? bk  : bq;
    bf16*        Out  = isK ? Ko  : Qo;
    const float  scale = isK ? 1.0f : 0.125f;
    const int m0 = blockIdx.x * 128, n0 = (blockIdx.y & 7) * 128;

    f32x4 acc[4][4] = {};
    gemm_core_128(A, Bt, m0, n0, As, Bs, acc);

    const int lane = threadIdx.x & 63, wave = threadIdx.x >> 6;
    const int lr = lane & 15, lg = lane >> 4;
    const int wr = wave >> 1, wc = wave & 1;
    #pragma unroll
    for (int i = 0; i < 4; ++i)
        #pragma unroll
        for (int j = 0; j < 4; ++j)
            #pragma unroll
            for (int r = 0; r < 4; ++r) {
                const int m = m0 + wr * 64 + i * 16 + lg * 4 + r;
                const int n = n0 + wc * 64 + j * 16 + lr;
                const float val = (acc[i][j][r] + bias[n]) * scale;
                const int b = m >> 11, t = m & (T_ - 1);
                const int h = n >> 6, hd = n & 63;
                Out[((size_t)((b * H_ + h) * T_ + t)) * HD_ + hd] = (bf16)val;
            }
}

// ---------------- V^T projection: C[d_glob][t] = sum_k WvT[d][k] x[t][k] ----------------
__global__ __launch_bounds__(256) void gemm_vt_kernel(
    const bf16* __restrict__ WvT, const bf16* __restrict__ Xb,
    const float* __restrict__ bv, bf16* __restrict__ Vt)
{
    __shared__ bf16 As[128][64];
    __shared__ bf16 Bs[128][64];
    const int m0 = blockIdx.x * 128, n0 = blockIdx.y * 128;  // m over 1024 (d), n over 4096 (b*t)

    f32x4 acc[4][4] = {};
    gemm_core_128(WvT, Xb, m0, n0, As, Bs, acc);

    const int lane = threadIdx.x & 63, wave = threadIdx.x >> 6;
    const int lr = lane & 15, lg = lane >> 4;
    const int wr = wave >> 1, wc = wave & 1;
    #pragma unroll
    for (int i = 0; i < 4; ++i)
        #pragma unroll
        for (int j = 0; j < 4; ++j)
            #pragma unroll
            for (int r = 0; r < 4; ++r) {
                const int m = m0 + wr * 64 + i * 16 + lg * 4 + r;   // d_glob
                const int n = n0 + wc * 64 + j * 16 + lr;            // b*2048 + t
                const float val = acc[i][j][r] + bv[m];
                const int b = n >> 11, t = n & (T_ - 1);
                Vt[((size_t)(b * D_ + m)) * T_ + t] = (bf16)val;
            }
}

// ---------------- out projection: fp32 [m][n] ----------------
__global__ __launch_bounds__(256) void gemm_out_kernel(
    const bf16* __restrict__ A, const bf16* __restrict__ WoT,
    const float* __restrict__ bo, float* __restrict__ Out)
{
    __shared__ bf16 As[128][64];
    __shared__ bf16 Bs[128][64];
    const int m0 = blockIdx.x * 128, n0 = blockIdx.y * 128;

    f32x4 acc[4][4] = {};
    gemm_core_128(A, WoT, m0, n0, As, Bs, acc);

    const int lane = threadIdx.x & 63, wave = threadIdx.x >> 6;
    const int lr = lane & 15, lg = lane >> 4;
    const int wr = wave >> 1, wc = wave & 1;
    #pragma unroll
    for (int i = 0; i < 4; ++i)
        #pragma unroll
        for (int j = 0; j < 4; ++j)
            #pragma unroll
            for (int r = 0; r < 4; ++r) {
                const int m = m0 + wr * 64 + i * 16 + lg * 4 + r;
                const int n = n0 + wc * 64 + j * 16 + lr;
                Out[(size_t)m * D_ + n] = acc[i][j][r] + bo[n];
            }
}

// ---------------- flash attention (8 waves, QBLK=128, swapped QK^T) ----------------
// Q,K: [bh][t][64] bf16 (Q pre-scaled 1/8). Vt: [bh][64][T] bf16.
// Block x handles q-super-blocks x and 15-x (34 KV tiles total -> balanced).
// Swapped QK^T: S'[key][q] = mfma(A=K, B=Q) -> softmax row is lane-local-ish
// (q = lane&15; keys split over the 4 lane-groups -> 2 shfl_xor reduce).
__global__ __launch_bounds__(512) void attn_kernel(
    const bf16* __restrict__ Q, const bf16* __restrict__ K,
    const bf16* __restrict__ Vt, bf16* __restrict__ Out)
{
    const int bh = blockIdx.y;
    const int tid = threadIdx.x, wave = tid >> 6, lane = tid & 63;
    const int lr = lane & 15, lg = lane >> 4;
    const size_t kbase = (size_t)bh * T_ * HD_;   // Q,K
    const size_t vbase = (size_t)bh * HD_ * T_;   // Vt

    __shared__ bf16 Ks[2][64][64];   // 16 KB
    __shared__ bf16 Vs[2][64][64];   // 16 KB  (Vs[buf][d][key])
    __shared__ bf16 Ps[8][16][72];   // 18 KB  per-wave P[q][key], padded

    // stage one 64-key tile into buffer sb; XOR source-chunk swizzle (involution)
    auto stage = [&](int sb, int kt) {
        const int kv0 = kt * 64;
        const int rseg = lane >> 3;              // 0..7
        const int srcw = (lane & 7) ^ rseg;      // source 16B-chunk
        const int row  = wave * 8 + rseg;        // 0..63
        GLOAD_LDS(K  + kbase + (size_t)(kv0 + row) * HD_ + srcw * 8, &Ks[sb][wave * 8][0]);
        GLOAD_LDS(Vt + vbase + (size_t)row * T_ + kv0 + srcw * 8,    &Vs[sb][wave * 8][0]);
    };
    auto kfrag = [&](int sb, int row, int chunk) {
        return *reinterpret_cast<const bf16x8*>(&Ks[sb][row][(chunk ^ (row & 7)) * 8]);
    };
    auto vfrag = [&](int sb, int row, int chunk) {
        return *reinterpret_cast<const bf16x8*>(&Vs[sb][row][(chunk ^ (row & 7)) * 8]);
    };

    #pragma unroll 1
    for (int half = 0; half < 2; ++half) {
        const int qb = half == 0 ? blockIdx.x : (NQB - 1 - blockIdx.x);
        const int q0 = qb * 128;                 // this block's 128 q-rows
        const int nt = 2 * qb + 2;               // KV tiles of 64 needed
        const int qw = wave * 16;                // wave's q-offset within block

        // Q fragments for this wave's 16 rows (B-operand: col=lane&15 -> q=lr)
        bf16x8 qf[2];
        {
            const bf16* qrow = Q + kbase + (size_t)(q0 + qw + lr) * HD_;
            qf[0] = *reinterpret_cast<const bf16x8*>(qrow + lg * 8);
            qf[1] = *reinterpret_cast<const bf16x8*>(qrow + 32 + lg * 8);
        }

        float m_s = -1e30f, l_s = 0.f;           // softmax state for q = q0+qw+lr
        f32x4 o_acc[4] = {};                     // O[q=qw+lg*4+r][d=nd*16+lr]

        stage(0, 0);
        __syncthreads();

        #pragma unroll 1
        for (int t = 0; t < nt; ++t) {
            const int cur = t & 1;
            if (t + 1 < nt) stage(cur ^ 1, t + 1);  // prefetch next tile

            const int kv0 = t * 64;
            // wave-uniform skip: all 16 q-rows of this wave < kv0 -> fully masked
            if (kv0 <= q0 + qw + 15) {
                // S'[key][q]: key = kv0 + n16*16 + lg*4 + r, q = q0 + qw + lr
                f32x4 s[4] = {};
                #pragma unroll
                for (int n16 = 0; n16 < 4; ++n16)
                    #pragma unroll
                    for (int kk = 0; kk < 2; ++kk)
                        s[n16] = __builtin_amdgcn_mfma_f32_16x16x32_bf16(
                            kfrag(cur, n16 * 16 + lr, kk * 4 + lg), qf[kk], s[n16], 0, 0, 0);
                // causal mask on the last two (partial) tiles
                if (t >= 2 * qb) {
                    #pragma unroll
                    for (int n16 = 0; n16 < 4; ++n16)
                        #pragma unroll
                        for (int r = 0; r < 4; ++r)
                            if (kv0 + n16 * 16 + lg * 4 + r > q0 + qw + lr)
                                s[n16][r] = -1e30f;
                }
                // online softmax: lane holds 16 of the 64 keys for q = lr-row
                float mx = s[0][0];
                #pragma unroll
                for (int n16 = 0; n16 < 4; ++n16)
                    #pragma unroll
                    for (int r = 0; r < 4; ++r)
                        mx = fmaxf(mx, s[n16][r]);
                mx = fmaxf(mx, __shfl_xor(mx, 16));
                mx = fmaxf(mx, __shfl_xor(mx, 32));
                const float mnew  = fmaxf(m_s, mx);
                const float alpha = __expf(m_s - mnew);
                float rs = 0.f;
                #pragma unroll
                for (int n16 = 0; n16 < 4; ++n16) {
                    bf16x4 pw;
                    #pragma unroll
                    for (int r = 0; r < 4; ++r) {
                        const float p = __expf(s[n16][r] - mnew);
                        rs += p;
                        pw[r] = (bf16)p;
                    }
                    *reinterpret_cast<bf16x4*>(&Ps[wave][lr][n16 * 16 + lg * 4]) = pw;
                }
                rs += __shfl_xor(rs, 16);
                rs += __shfl_xor(rs, 32);
                l_s = l_s * alpha + rs;
                m_s = mnew;
                // rescale O: need alpha of q = qw + lg*4 + r -> lane lg*4+r
                #pragma unroll
                for (int r = 0; r < 4; ++r) {
                    const float a = __shfl(alpha, lg * 4 + r);
                    #pragma unroll
                    for (int nd = 0; nd < 4; ++nd) o_acc[nd][r] *= a;
                }
                // O += P @ V
                #pragma unroll
                for (int ks = 0; ks < 2; ++ks) {
                    const bf16x8 pa = *reinterpret_cast<const bf16x8*>(&Ps[wave][lr][ks * 32 + lg * 8]);
                    #pragma unroll
                    for (int nd = 0; nd < 4; ++nd)
                        o_acc[nd] = __builtin_amdgcn_mfma_f32_16x16x32_bf16(
                            pa, vfrag(cur, nd * 16 + lr, ks * 4 + lg), o_acc[nd], 0, 0, 0);
                }
            }
            __syncthreads();  // all reads of cur done; next tile fully staged
        }

        // normalize + store to [b*T+t][h*64+d]
        const int b = bh >> 4, h = bh & 15;
        const float linv = 1.0f / l_s;
        #pragma unroll
        for (int r = 0; r < 4; ++r) {
            const float li = __shfl(linv, lg * 4 + r);
            const int q = q0 + qw + lg * 4 + r;
            #pragma unroll
            for (int nd = 0; nd < 4; ++nd) {
                const int d = nd * 16 + lr;
                Out[((size_t)(b * T_ + q)) * D_ + h * HD_ + d] = (bf16)(o_acc[nd][r] * li);
            }
        }
    }
}

// ---------------- launch ----------------
extern "C" void kernel_launch(void* const* d_in, const int* in_sizes, int n_in,
                              void* d_out, int out_size, void* d_ws, size_t ws_size,
                              hipStream_t stream) {
    const float* x  = (const float*)d_in[0];
    const float* Wq = (const float*)d_in[1];
    const float* bq = (const float*)d_in[2];
    const float* Wk = (const float*)d_in[3];
    const float* bk = (const float*)d_in[4];
    const float* Wv = (const float*)d_in[5];
    const float* bv = (const float*)d_in[6];
    const float* Wo = (const float*)d_in[7];
    const float* bo = (const float*)d_in[8];
    float* out = (float*)d_out;

    char* ws = (char*)d_ws;
    bf16* xb   = (bf16*)(ws);                         // 8 MB  [4096][1024]
    bf16* WqT  = (bf16*)(ws + ( 8u << 20));           // 2 MB  [1024][1024]
    bf16* WkT  = (bf16*)(ws + (10u << 20));
    bf16* WvT  = (bf16*)(ws + (12u << 20));
    bf16* WoT  = (bf16*)(ws + (14u << 20));
    bf16* Qb   = (bf16*)(ws + (16u << 20));           // 8 MB  [32][2048][64]
    bf16* Kb   = (bf16*)(ws + (24u << 20));
    bf16* Vtb  = (bf16*)(ws + (32u << 20));           // 8 MB  [32][64][2048]
    bf16* attn = (bf16*)(ws + (40u << 20));           // 8 MB  [4096][1024]

    cast_x_kernel<<<4096, 256, 0, stream>>>(x, xb);
    transpose_cast_kernel<<<dim3(32, 32, 4), 256, 0, stream>>>(
        Wq, WqT, Wk, WkT, Wv, WvT, Wo, WoT);

    gemm_qk_kernel<<<dim3(32, 16), 256, 0, stream>>>(xb, WqT, bq, Qb, WkT, bk, Kb);
    gemm_vt_kernel<<<dim3(8, 32), 256, 0, stream>>>(WvT, xb, bv, Vtb);

    attn_kernel<<<dim3(NQB / 2, 32), 512, 0, stream>>>(Qb, Kb, Vtb, attn);

    gemm_out_kernel<<<dim3(32, 8), 256, 0, stream>>>(attn, WoT, bo, out);
}

// Round 4
// 135.985 us; speedup vs baseline: 2.4122x; 1.0321x over previous
//
#include <hip/hip_runtime.h>
#include <cstdint>
#include <cstddef>

typedef __bf16 bf16;
typedef __bf16 bf16x4 __attribute__((ext_vector_type(4)));
typedef __bf16 bf16x8 __attribute__((ext_vector_type(8)));
typedef float  f32x4  __attribute__((ext_vector_type(4)));

#define B_  2
#define T_  2048
#define D_  1024
#define H_  16
#define HD_ 64
#define M_  (B_ * T_)   // 4096 rows
#define NQB 16          // T_/128 q-super-blocks

#define GLOAD_LDS(gsrc, ldst) \
    __builtin_amdgcn_global_load_lds( \
        (const __attribute__((address_space(1))) void*)(gsrc), \
        (__attribute__((address_space(3))) void*)(ldst), 16, 0, 0)

__device__ __forceinline__ void barrier_pin() {
    asm volatile("" ::: "memory");
    __builtin_amdgcn_s_barrier();
    asm volatile("" ::: "memory");
}

// ---------------- cast x (fp32 -> bf16) ----------------
__global__ void cast_x_kernel(const float* __restrict__ in, bf16* __restrict__ out) {
    int i = (blockIdx.x * 256 + threadIdx.x) * 4;
    const float4 v = *reinterpret_cast<const float4*>(in + i);
    bf16x4 o = { (bf16)v.x, (bf16)v.y, (bf16)v.z, (bf16)v.w };
    *reinterpret_cast<bf16x4*>(out + i) = o;
}

// ---------------- transpose + cast 4 weights: Wt[n][k] = W[k][n] ----------------
__global__ void transpose_cast_kernel(
    const float* __restrict__ W0, bf16* __restrict__ T0,
    const float* __restrict__ W1, bf16* __restrict__ T1,
    const float* __restrict__ W2, bf16* __restrict__ T2,
    const float* __restrict__ W3, bf16* __restrict__ T3)
{
    __shared__ float tile[32][33];
    const float* W = blockIdx.z == 0 ? W0 : blockIdx.z == 1 ? W1 : blockIdx.z == 2 ? W2 : W3;
    bf16*       Wt = blockIdx.z == 0 ? T0 : blockIdx.z == 1 ? T1 : blockIdx.z == 2 ? T2 : T3;
    const int tx = threadIdx.x & 31, ty = threadIdx.x >> 5;  // 32 x 8
    const int bx = blockIdx.x * 32, by = blockIdx.y * 32;
    #pragma unroll
    for (int r = 0; r < 32; r += 8)
        tile[ty + r][tx] = W[(size_t)(by + ty + r) * D_ + bx + tx];
    __syncthreads();
    #pragma unroll
    for (int r = 0; r < 32; r += 8)
        Wt[(size_t)(bx + ty + r) * D_ + by + tx] = (bf16)tile[tx][ty + r];
}

// ================= 256x256 8-phase QKV kernel (T1+T2+T3+T4+T5) =================
// Roles by swizzled block id: [0,128): QK (A=xb tokens, Bt=WqT/WkT);
//                             [128,192): VT (A=WvT d-rows, Bt=xb tokens).
// BM=BN=256, BK=64, 8 waves (2Mx4N), LDS = 2dbuf x 2half x 128x64 x {A,B} = 128 KiB.
// A-halves are 64-row stripes {h*64, 128+h*64}; B-halves are 32-row stripes.
// Quadrants per K-tile: q0=(A0,B0) q1=(A0,B1) q2=(A1,B1) q3=(A1,B0).
// Issue schedule (per tile t): p0:(t+1)#3=A[c'][1], p1:(t+1)#4=B[c'][0],
//                              p2:(t+2)#1=A[c][0],  p3:(t+2)#2=B[c][1].
// vmcnt(6) once per tile at p0 (3 half-tiles = 6 loads stay in flight).
__global__ __launch_bounds__(512, 2) void qkv256_kernel(
    const bf16* __restrict__ xb,
    const bf16* __restrict__ WqT, const float* __restrict__ bq, bf16* __restrict__ Qo,
    const bf16* __restrict__ WkT, const float* __restrict__ bk, bf16* __restrict__ Ko,
    const bf16* __restrict__ WvT, const float* __restrict__ bv, bf16* __restrict__ Vt)
{
    __shared__ bf16 As[2][2][128][64];   // 64 KiB
    __shared__ bf16 Bs[2][2][128][64];   // 64 KiB

    const int bid = blockIdx.x;
    const int swz = (bid & 7) * 24 + (bid >> 3);       // XCD-bijective (192 % 8 == 0)
    const int tid = threadIdx.x, wave = tid >> 6, lane = tid & 63;
    const int lr = lane & 15, lg = lane >> 4;
    const int wr = wave >> 2, wc = wave & 3;

    const bf16 *Aop, *Bop;
    const float *bias;
    bf16 *outp;
    float scale = 1.0f;
    int mbase, nbase, mode;
    if (swz < 128) {
        const int bm = swz >> 3, bn = swz & 7;
        mbase = bm * 256;                               // token rows
        nbase = (bn & 3) * 256;                         // col within Wq or Wk
        Aop = xb + (size_t)mbase * D_;
        if (bn < 4) { Bop = WqT + (size_t)nbase * D_; bias = bq; outp = Qo; scale = 0.125f; }
        else        { Bop = WkT + (size_t)nbase * D_; bias = bk; outp = Ko; }
        mode = 0;
    } else {
        const int v = swz - 128, bm = v >> 4, bn = v & 15;
        mbase = bm * 256;                               // d rows
        nbase = bn * 256;                               // token cols
        Aop = WvT + (size_t)mbase * D_;
        Bop = xb  + (size_t)nbase * D_;
        bias = bv; outp = Vt; mode = 1;
    }

    // ---- staging: one half-tile = 2 gload_lds per wave; XOR source-chunk swizzle ----
    const int r8   = lane >> 3;
    const int srcc = (lane & 7) ^ r8;
    auto stageA = [&](int c, int h, int kt) {
        #pragma unroll
        for (int l = 0; l < 2; ++l) {
            const int cr  = wave * 2 + l;
            const int loc = cr * 8 + r8;                            // 0..127
            const int rho = h * 64 + (loc & 63) + ((loc >> 6) << 7); // stripe map
            GLOAD_LDS(Aop + (size_t)rho * D_ + kt * 64 + srcc * 8, &As[c][h][cr * 8][0]);
        }
    };
    auto stageB = [&](int c, int h, int kt) {
        #pragma unroll
        for (int l = 0; l < 2; ++l) {
            const int cr  = wave * 2 + l;
            const int loc = cr * 8 + r8;
            const int rho = h * 32 + (loc & 31) + ((loc >> 5) << 6);
            GLOAD_LDS(Bop + (size_t)rho * D_ + kt * 64 + srcc * 8, &Bs[c][h][cr * 8][0]);
        }
    };

    f32x4 acc[8][4] = {};
    bf16x8 ar[4][2], b0r[2][2], b1r[2][2];

    auto LDA = [&](int c, int mh) {
        #pragma unroll
        for (int i = 0; i < 4; ++i)
            #pragma unroll
            for (int kk = 0; kk < 2; ++kk)
                ar[i][kk] = *reinterpret_cast<const bf16x8*>(
                    &As[c][mh][wr * 64 + i * 16 + lr][(((kk * 4 + lg)) ^ (lr & 7)) * 8]);
    };
    auto LDB = [&](int c, int nh, bf16x8 (&br)[2][2]) {
        #pragma unroll
        for (int j = 0; j < 2; ++j)
            #pragma unroll
            for (int kk = 0; kk < 2; ++kk)
                br[j][kk] = *reinterpret_cast<const bf16x8*>(
                    &Bs[c][nh][wc * 32 + j * 16 + lr][(((kk * 4 + lg)) ^ (lr & 7)) * 8]);
    };
    auto QUAD = [&](const bf16x8 (&br)[2][2], int mh, int nh) {
        __builtin_amdgcn_s_setprio(1);
        #pragma unroll
        for (int i = 0; i < 4; ++i)
            #pragma unroll
            for (int j = 0; j < 2; ++j)
                #pragma unroll
                for (int kk = 0; kk < 2; ++kk)
                    acc[mh * 4 + i][nh * 2 + j] = __builtin_amdgcn_mfma_f32_16x16x32_bf16(
                        ar[i][kk], br[j][kk], acc[mh * 4 + i][nh * 2 + j], 0, 0, 0);
        __builtin_amdgcn_s_setprio(0);
    };

    constexpr int NK = D_ / 64;   // 16 K-tiles
    // prologue: tile0 all 4 halves + tile1 halves #1,#2 (issue order = wait order)
    stageA(0, 0, 0); stageB(0, 1, 0); stageA(0, 1, 0); stageB(0, 0, 0);
    stageA(1, 0, 1); stageB(1, 1, 1);

    #pragma unroll 1
    for (int t = 0; t < NK; ++t) {
        const int c = t & 1, cn = c ^ 1;
        const int t1 = (t + 1 < NK) ? t + 1 : NK - 1;
        const int t2 = (t + 2 < NK) ? t + 2 : NK - 1;
        // ---- phase 0: quadrant (A0,B0) ----
        stageA(cn, 1, t1);                               // (t+1)#3
        asm volatile("s_waitcnt vmcnt(6)" ::: "memory"); // tile t fully resident (own ops)
        barrier_pin();                                   // publish to all waves
        LDA(c, 0); LDB(c, 0, b0r);
        QUAD(b0r, 0, 0);
        barrier_pin();
        // ---- phase 1: quadrant (A0,B1) ----
        stageB(cn, 0, t1);                               // (t+1)#4
        LDB(c, 1, b1r);
        barrier_pin();
        QUAD(b1r, 0, 1);
        barrier_pin();
        // ---- phase 2: quadrant (A1,B1) ----
        stageA(c, 0, t2);                                // (t+2)#1 (A[c][0] dead since p1)
        LDA(c, 1);
        barrier_pin();
        QUAD(b1r, 1, 1);
        barrier_pin();
        // ---- phase 3: quadrant (A1,B0) ----
        stageB(c, 1, t2);                                // (t+2)#2 (B[c][1] dead since p2)
        barrier_pin();
        QUAD(b0r, 1, 0);                                 // B0 still in regs from p0
        barrier_pin();
    }

    // ---- epilogue ----
    if (mode == 0) {
        #pragma unroll
        for (int i = 0; i < 8; ++i)
            #pragma unroll
            for (int j = 0; j < 4; ++j)
                #pragma unroll
                for (int r = 0; r < 4; ++r) {
                    const int m  = mbase + wr * 128 + i * 16 + lg * 4 + r;   // token
                    const int nw = nbase + wc * 64 + j * 16 + lr;            // 0..1023
                    const float val = (acc[i][j][r] + bias[nw]) * scale;
                    const int b = m >> 11, tt = m & (T_ - 1);
                    const int h = nw >> 6, hd = nw & 63;
                    outp[((size_t)((b * H_ + h) * T_ + tt)) * HD_ + hd] = (bf16)val;
                }
    } else {
        #pragma unroll
        for (int i = 0; i < 8; ++i)
            #pragma unroll
            for (int j = 0; j < 4; ++j)
                #pragma unroll
                for (int r = 0; r < 4; ++r) {
                    const int d = mbase + wr * 128 + i * 16 + lg * 4 + r;    // 0..1023
                    const int n = nbase + wc * 64 + j * 16 + lr;             // token
                    const int b = n >> 11, tt = n & (T_ - 1);
                    outp[((size_t)(b * D_ + d)) * T_ + tt] = (bf16)(acc[i][j][r] + bias[d]);
                }
    }
}

// ---------------- 128x128 core (kept for out-projection) ----------------
__device__ __forceinline__ void gemm_core_128(
    const bf16* __restrict__ A, const bf16* __restrict__ Bt,
    int m0, int n0, bf16 (*As)[64], bf16 (*Bs)[64], f32x4 acc[4][4])
{
    constexpr int K = D_;
    const int tid  = threadIdx.x;
    const int wave = tid >> 6, lane = tid & 63;
    const int lr = lane & 15, lg = lane >> 4;
    const int wr = wave >> 1, wc = wave & 1;

    for (int k0 = 0; k0 < K; k0 += 64) {
        #pragma unroll
        for (int cc = 0; cc < 4; ++cc) {
            const int c   = wave * 4 + cc;
            const int row = c * 8 + (lane >> 3);
            const int col = (lane & 7) * 8;
            GLOAD_LDS(A  + (size_t)(m0 + row) * K + k0 + col, &As[c * 8][0]);
            GLOAD_LDS(Bt + (size_t)(n0 + row) * K + k0 + col, &Bs[c * 8][0]);
        }
        __syncthreads();
        #pragma unroll
        for (int kk = 0; kk < 64; kk += 32) {
            bf16x8 af[4], bfr[4];
            #pragma unroll
            for (int i = 0; i < 4; ++i)
                af[i] = *reinterpret_cast<const bf16x8*>(&As[wr * 64 + i * 16 + lr][kk + lg * 8]);
            #pragma unroll
            for (int j = 0; j < 4; ++j)
                bfr[j] = *reinterpret_cast<const bf16x8*>(&Bs[wc * 64 + j * 16 + lr][kk + lg * 8]);
            #pragma unroll
            for (int i = 0; i < 4; ++i)
                #pragma unroll
                for (int j = 0; j < 4; ++j)
                    acc[i][j] = __builtin_amdgcn_mfma_f32_16x16x32_bf16(af[i], bfr[j], acc[i][j], 0, 0, 0);
        }
        __syncthreads();
    }
}

// ---------------- out projection: fp32 [m][n] ----------------
__global__ __launch_bounds__(256) void gemm_out_kernel(
    const bf16* __restrict__ A, const bf16* __restrict__ WoT,
    const float* __restrict__ bo, float* __restrict__ Out)
{
    __shared__ bf16 As[128][64];
    __shared__ bf16 Bs[128][64];
    const int m0 = blockIdx.x * 128, n0 = blockIdx.y * 128;

    f32x4 acc[4][4] = {};
    gemm_core_128(A, WoT, m0, n0, As, Bs, acc);

    const int lane = threadIdx.x & 63, wave = threadIdx.x >> 6;
    const int lr = lane & 15, lg = lane >> 4;
    const int wr = wave >> 1, wc = wave & 1;
    #pragma unroll
    for (int i = 0; i < 4; ++i)
        #pragma unroll
        for (int j = 0; j < 4; ++j)
            #pragma unroll
            for (int r = 0; r < 4; ++r) {
                const int m = m0 + wr * 64 + i * 16 + lg * 4 + r;
                const int n = n0 + wc * 64 + j * 16 + lr;
                Out[(size_t)m * D_ + n] = acc[i][j][r] + bo[n];
            }
}

// ---------------- flash attention (8 waves, QBLK=128, swapped QK^T) ----------------
__global__ __launch_bounds__(512) void attn_kernel(
    const bf16* __restrict__ Q, const bf16* __restrict__ K,
    const bf16* __restrict__ Vt, bf16* __restrict__ Out)
{
    const int bh = blockIdx.y;
    const int tid = threadIdx.x, wave = tid >> 6, lane = tid & 63;
    const int lr = lane & 15, lg = lane >> 4;
    const size_t kbase = (size_t)bh * T_ * HD_;   // Q,K
    const size_t vbase = (size_t)bh * HD_ * T_;   // Vt

    __shared__ bf16 Ks[2][64][64];   // 16 KB
    __shared__ bf16 Vs[2][64][64];   // 16 KB  (Vs[buf][d][key])
    __shared__ bf16 Ps[8][16][72];   // 18 KB  per-wave P[q][key], padded

    auto stage = [&](int sb, int kt) {
        const int kv0 = kt * 64;
        const int rseg = lane >> 3;
        const int srcw = (lane & 7) ^ rseg;
        const int row  = wave * 8 + rseg;
        GLOAD_LDS(K  + kbase + (size_t)(kv0 + row) * HD_ + srcw * 8, &Ks[sb][wave * 8][0]);
        GLOAD_LDS(Vt + vbase + (size_t)row * T_ + kv0 + srcw * 8,    &Vs[sb][wave * 8][0]);
    };
    auto kfrag = [&](int sb, int row, int chunk) {
        return *reinterpret_cast<const bf16x8*>(&Ks[sb][row][(chunk ^ (row & 7)) * 8]);
    };
    auto vfrag = [&](int sb, int row, int chunk) {
        return *reinterpret_cast<const bf16x8*>(&Vs[sb][row][(chunk ^ (row & 7)) * 8]);
    };

    #pragma unroll 1
    for (int half = 0; half < 2; ++half) {
        const int qb = half == 0 ? blockIdx.x : (NQB - 1 - blockIdx.x);
        const int q0 = qb * 128;
        const int nt = 2 * qb + 2;
        const int qw = wave * 16;

        bf16x8 qf[2];
        {
            const bf16* qrow = Q + kbase + (size_t)(q0 + qw + lr) * HD_;
            qf[0] = *reinterpret_cast<const bf16x8*>(qrow + lg * 8);
            qf[1] = *reinterpret_cast<const bf16x8*>(qrow + 32 + lg * 8);
        }

        float m_s = -1e30f, l_s = 0.f;
        f32x4 o_acc[4] = {};

        stage(0, 0);
        __syncthreads();

        #pragma unroll 1
        for (int t = 0; t < nt; ++t) {
            const int cur = t & 1;
            if (t + 1 < nt) stage(cur ^ 1, t + 1);

            const int kv0 = t * 64;
            if (kv0 <= q0 + qw + 15) {
                f32x4 s[4] = {};
                __builtin_amdgcn_s_setprio(1);
                #pragma unroll
                for (int n16 = 0; n16 < 4; ++n16)
                    #pragma unroll
                    for (int kk = 0; kk < 2; ++kk)
                        s[n16] = __builtin_amdgcn_mfma_f32_16x16x32_bf16(
                            kfrag(cur, n16 * 16 + lr, kk * 4 + lg), qf[kk], s[n16], 0, 0, 0);
                __builtin_amdgcn_s_setprio(0);
                if (t >= 2 * qb) {
                    #pragma unroll
                    for (int n16 = 0; n16 < 4; ++n16)
                        #pragma unroll
                        for (int r = 0; r < 4; ++r)
                            if (kv0 + n16 * 16 + lg * 4 + r > q0 + qw + lr)
                                s[n16][r] = -1e30f;
                }
                float mx = s[0][0];
                #pragma unroll
                for (int n16 = 0; n16 < 4; ++n16)
                    #pragma unroll
                    for (int r = 0; r < 4; ++r)
                        mx = fmaxf(mx, s[n16][r]);
                mx = fmaxf(mx, __shfl_xor(mx, 16));
                mx = fmaxf(mx, __shfl_xor(mx, 32));
                const float mnew  = fmaxf(m_s, mx);
                const float alpha = __expf(m_s - mnew);
                float rs = 0.f;
                #pragma unroll
                for (int n16 = 0; n16 < 4; ++n16) {
                    bf16x4 pw;
                    #pragma unroll
                    for (int r = 0; r < 4; ++r) {
                        const float p = __expf(s[n16][r] - mnew);
                        rs += p;
                        pw[r] = (bf16)p;
                    }
                    *reinterpret_cast<bf16x4*>(&Ps[wave][lr][n16 * 16 + lg * 4]) = pw;
                }
                rs += __shfl_xor(rs, 16);
                rs += __shfl_xor(rs, 32);
                l_s = l_s * alpha + rs;
                m_s = mnew;
                #pragma unroll
                for (int r = 0; r < 4; ++r) {
                    const float a = __shfl(alpha, lg * 4 + r);
                    #pragma unroll
                    for (int nd = 0; nd < 4; ++nd) o_acc[nd][r] *= a;
                }
                __builtin_amdgcn_s_setprio(1);
                #pragma unroll
                for (int ks = 0; ks < 2; ++ks) {
                    const bf16x8 pa = *reinterpret_cast<const bf16x8*>(&Ps[wave][lr][ks * 32 + lg * 8]);
                    #pragma unroll
                    for (int nd = 0; nd < 4; ++nd)
                        o_acc[nd] = __builtin_amdgcn_mfma_f32_16x16x32_bf16(
                            pa, vfrag(cur, nd * 16 + lr, ks * 4 + lg), o_acc[nd], 0, 0, 0);
                }
                __builtin_amdgcn_s_setprio(0);
            }
            __syncthreads();
        }

        const int b = bh >> 4, h = bh & 15;
        const float linv = 1.0f / l_s;
        #pragma unroll
        for (int r = 0; r < 4; ++r) {
            const float li = __shfl(linv, lg * 4 + r);
            const int q = q0 + qw + lg * 4 + r;
            #pragma unroll
            for (int nd = 0; nd < 4; ++nd) {
                const int d = nd * 16 + lr;
                Out[((size_t)(b * T_ + q)) * D_ + h * HD_ + d] = (bf16)(o_acc[nd][r] * li);
            }
        }
    }
}

// ---------------- launch ----------------
extern "C" void kernel_launch(void* const* d_in, const int* in_sizes, int n_in,
                              void* d_out, int out_size, void* d_ws, size_t ws_size,
                              hipStream_t stream) {
    const float* x  = (const float*)d_in[0];
    const float* Wq = (const float*)d_in[1];
    const float* bq = (const float*)d_in[2];
    const float* Wk = (const float*)d_in[3];
    const float* bk = (const float*)d_in[4];
    const float* Wv = (const float*)d_in[5];
    const float* bv = (const float*)d_in[6];
    const float* Wo = (const float*)d_in[7];
    const float* bo = (const float*)d_in[8];
    float* out = (float*)d_out;

    char* ws = (char*)d_ws;
    bf16* xb   = (bf16*)(ws);                         // 8 MB  [4096][1024]
    bf16* WqT  = (bf16*)(ws + ( 8u << 20));           // 2 MB  [1024][1024]
    bf16* WkT  = (bf16*)(ws + (10u << 20));
    bf16* WvT  = (bf16*)(ws + (12u << 20));
    bf16* WoT  = (bf16*)(ws + (14u << 20));
    bf16* Qb   = (bf16*)(ws + (16u << 20));           // 8 MB  [32][2048][64]
    bf16* Kb   = (bf16*)(ws + (24u << 20));
    bf16* Vtb  = (bf16*)(ws + (32u << 20));           // 8 MB  [32][64][2048]
    bf16* attn = (bf16*)(ws + (40u << 20));           // 8 MB  [4096][1024]

    cast_x_kernel<<<4096, 256, 0, stream>>>(x, xb);
    transpose_cast_kernel<<<dim3(32, 32, 4), 256, 0, stream>>>(
        Wq, WqT, Wk, WkT, Wv, WvT, Wo, WoT);

    qkv256_kernel<<<192, 512, 0, stream>>>(xb, WqT, bq, Qb, WkT, bk, Kb, WvT, bv, Vtb);

    attn_kernel<<<dim3(NQB / 2, 32), 512, 0, stream>>>(Qb, Kb, Vtb, attn);

    gemm_out_kernel<<<dim3(32, 8), 256, 0, stream>>>(attn, WoT, bo, out);
}